// Round 6
// baseline (194.741 us; speedup 1.0000x reference)
//
#include <hip/hip_runtime.h>
#include <hip/hip_bf16.h>

// Problem constants
#define SEQ   2048
#define INF_  512          // IN dim
#define HQ    16           // query heads
#define KVH   4            // kv heads
#define DH    64           // head dim
#define NQ    (HQ*DH)      // 1024
#define NKV   (KVH*DH)     // 256
#define OUTD  512

typedef short v8s __attribute__((ext_vector_type(8)));   // 8 bf16 (4 VGPRs)
typedef float v4f __attribute__((ext_vector_type(4)));   // 4 fp32 acc

static __device__ __forceinline__ float bf2f(unsigned short u) {
    union { unsigned int i; float f; } c;
    c.i = ((unsigned int)u) << 16;
    return c.f;
}
static __device__ __forceinline__ unsigned short f2bf(float f) {  // RNE
    union { float f; unsigned int i; } c; c.f = f;
    unsigned int lsb = (c.i >> 16) & 1u;
    c.i += 0x7fffu + lsb;
    return (unsigned short)(c.i >> 16);
}
static __device__ __forceinline__ unsigned int f2bf2(float lo, float hi) { // packed cvt
    union { __hip_bfloat162 h; unsigned int u; } c;
    c.h = __float22bfloat162_rn(make_float2(lo, hi));
    return c.u;
}
// pack two v4f (8 fp32) into one bf16x8 fragment
static __device__ __forceinline__ v8s pack8(v4f a, v4f b) {
    union { v8s s; uint4 u; } c;
    c.u = make_uint4(f2bf2(a[0], a[1]), f2bf2(a[2], a[3]),
                     f2bf2(b[0], b[1]), f2bf2(b[2], b[3]));
    return c.s;
}

// async global->LDS DMA, 16B per lane; lds base must be lane-invariant
static __device__ __forceinline__ void gll16(const void* g, void* l) {
    __builtin_amdgcn_global_load_lds(
        (const __attribute__((address_space(1))) void*)g,
        (__attribute__((address_space(3))) void*)l, 16, 0, 0);
}

// Stage one 64x64 bf16 tile (row-major src, given row stride) into LDS with
// XOR group swizzle applied via SOURCE addresses: LDS slot s of row r holds
// k-group s^(r&7). Wave w stages rows w*16..w*16+15 (2 DMA instrs).
static __device__ __forceinline__ void stage_tile(
    const unsigned short* __restrict__ src, int stride, int kb,
    unsigned short* ldsbase, int w, int lane)
{
#pragma unroll
    for (int i = 0; i < 2; i++) {
        const int rl = w * 16 + i * 8 + (lane >> 3);
        const int kc = ((lane & 7) ^ (rl & 7)) * 8;
        gll16(src + (size_t)rl * stride + kb + kc,
              ldsbase + (w * 16 + i * 8) * 64);
    }
}

// Same, for a 32x64 tile (wave w stages rows w*8..w*8+7, 1 DMA instr).
static __device__ __forceinline__ void stage_tile32(
    const unsigned short* __restrict__ src, int stride, int kb,
    unsigned short* ldsbase, int w, int lane)
{
    const int rl = w * 8 + (lane >> 3);
    const int kc = ((lane & 7) ^ (rl & 7)) * 8;
    gll16(src + (size_t)rl * stride + kb + kc,
          ldsbase + (w * 8) * 64);
}

#define QSCALE 0.180336880f   // 0.125 * log2(e): scores in log2 domain -> exp2

// ===========================================================================
// Cast kernel: x/Wq/Wk/Wv/Wo fp32 -> bf16 flat copies.
// ===========================================================================
__global__ __launch_bounds__(256) void cast_all(
    const float* __restrict__ x,  const float* __restrict__ Wq,
    const float* __restrict__ Wk, const float* __restrict__ Wv,
    const float* __restrict__ Wo,
    unsigned short* __restrict__ xb,  unsigned short* __restrict__ Wqb,
    unsigned short* __restrict__ Wkb, unsigned short* __restrict__ Wvb,
    unsigned short* __restrict__ Wob)
{
    size_t i = ((size_t)blockIdx.x * 256 + threadIdx.x) * 8;
    const float* s; unsigned short* d; size_t off;
    if (i < 1048576)      { s = x;  d = xb;  off = i; }
    else if (i < 1572864) { s = Wq; d = Wqb; off = i - 1048576; }
    else if (i < 1703936) { s = Wk; d = Wkb; off = i - 1572864; }
    else if (i < 1835008) { s = Wv; d = Wvb; off = i - 1703936; }
    else                  { s = Wo; d = Wob; off = i - 1835008; }
    float4 a = *(const float4*)(s + off);
    float4 b = *(const float4*)(s + off + 4);
    *(uint4*)(d + off) = make_uint4(f2bf2(a.x, a.y), f2bf2(a.z, a.w),
                                    f2bf2(b.x, b.y), f2bf2(b.z, b.w));
}

// ===========================================================================
// GEMM 1 (MFMA): QKV projection, bf16 in -> bf16 swizzled tile buffers.
// 64x64 tile, BK=64, gll16 DMA double-buffered staging, single barrier/iter,
// zero staging VALU. Grid 32x24. Epilogue tile formats unchanged:
//   Qg[t][h], Kg[g][t]: r*64 + ((d>>3)^(r&7))*8 + (d&7)  (Q pre-scaled)
//   Vg[g][t]: d*64 + swizzled j-permuted position.
// ===========================================================================
__global__ __launch_bounds__(256, 4) void gemm_qkv(
    const unsigned short* __restrict__ xb,
    const unsigned short* __restrict__ Wqb,
    const unsigned short* __restrict__ Wkb,
    const unsigned short* __restrict__ Wvb,
    unsigned short* __restrict__ Qg,
    unsigned short* __restrict__ Kg,
    unsigned short* __restrict__ Vg)
{
    __shared__ unsigned short Asb[2][4096];
    __shared__ unsigned short Bsb[2][4096];

    const int m0 = blockIdx.x * 64;
    const int n0 = blockIdx.y * 64;

    const unsigned short* Bp; int role;   // 0=Q 1=K 2=V
    if (n0 < NQ)            { Bp = Wqb + (size_t)n0 * INF_;              role = 0; }
    else if (n0 < NQ + NKV) { Bp = Wkb + (size_t)(n0 - NQ) * INF_;       role = 1; }
    else                    { Bp = Wvb + (size_t)(n0 - NQ - NKV) * INF_; role = 2; }

    const int tid = threadIdx.x;
    const int w = tid >> 6, lane = tid & 63;
    const int n = lane & 15, quad = lane >> 4;
    const int m7 = n & 7;
    const int r0w = (w & 1) * 32, c0w = (w >> 1) * 32;
    const unsigned short* Ap = xb + (size_t)m0 * INF_;

    v4f acc[2][2];
#pragma unroll
    for (int rt = 0; rt < 2; rt++)
#pragma unroll
        for (int ct = 0; ct < 2; ct++) acc[rt][ct] = (v4f){0.f,0.f,0.f,0.f};

    stage_tile(Ap, INF_, 0, &Asb[0][0], w, lane);
    stage_tile(Bp, INF_, 0, &Bsb[0][0], w, lane);

    for (int kb = 0; kb < INF_; kb += 64) {
        const int buf = (kb >> 6) & 1;
        __syncthreads();   // drains DMA; guards buf^1 reuse
        if (kb + 64 < INF_) {
            stage_tile(Ap, INF_, kb + 64, &Asb[buf ^ 1][0], w, lane);
            stage_tile(Bp, INF_, kb + 64, &Bsb[buf ^ 1][0], w, lane);
        }
#pragma unroll
        for (int kk = 0; kk < 2; kk++) {
            const int gs = ((kk * 4 + quad) ^ m7) * 8;
            v8s a0 = *(const v8s*)&Asb[buf][(r0w + n) * 64 + gs];
            v8s a1 = *(const v8s*)&Asb[buf][(r0w + 16 + n) * 64 + gs];
            v8s b0 = *(const v8s*)&Bsb[buf][(c0w + n) * 64 + gs];
            v8s b1 = *(const v8s*)&Bsb[buf][(c0w + 16 + n) * 64 + gs];
            acc[0][0] = __builtin_amdgcn_mfma_f32_16x16x32_bf16(a0, b0, acc[0][0], 0, 0, 0);
            acc[0][1] = __builtin_amdgcn_mfma_f32_16x16x32_bf16(a0, b1, acc[0][1], 0, 0, 0);
            acc[1][0] = __builtin_amdgcn_mfma_f32_16x16x32_bf16(a1, b0, acc[1][0], 0, 0, 0);
            acc[1][1] = __builtin_amdgcn_mfma_f32_16x16x32_bf16(a1, b1, acc[1][1], 0, 0, 0);
        }
    }

    const int t = m0 >> 6;
    if (role == 0) {
        unsigned short* base = Qg + ((size_t)(t * 16 + (n0 >> 6))) * 4096;
#pragma unroll
        for (int rt = 0; rt < 2; rt++)
#pragma unroll
            for (int ct = 0; ct < 2; ct++)
#pragma unroll
                for (int reg = 0; reg < 4; reg++) {
                    const int r = r0w + rt * 16 + quad * 4 + reg;
                    const int d = c0w + ct * 16 + n;
                    base[r * 64 + (((d >> 3) ^ (r & 7)) * 8) + (d & 7)] =
                        f2bf(acc[rt][ct][reg] * QSCALE);
                }
    } else if (role == 1) {
        const int g = (n0 - NQ) >> 6;
        unsigned short* base = Kg + ((size_t)(g * 32 + t)) * 4096;
#pragma unroll
        for (int rt = 0; rt < 2; rt++)
#pragma unroll
            for (int ct = 0; ct < 2; ct++)
#pragma unroll
                for (int reg = 0; reg < 4; reg++) {
                    const int r = r0w + rt * 16 + quad * 4 + reg;
                    const int d = c0w + ct * 16 + n;
                    base[r * 64 + (((d >> 3) ^ (r & 7)) * 8) + (d & 7)] =
                        f2bf(acc[rt][ct][reg]);
                }
    } else {
        const int g = (n0 - NQ - NKV) >> 6;
        unsigned short* base = Vg + ((size_t)(g * 32 + t)) * 4096;
#pragma unroll
        for (int rt = 0; rt < 2; rt++)
#pragma unroll
            for (int ct = 0; ct < 2; ct++) {
                const int jb_ = r0w + rt * 16 + quad * 4;  // 4 consecutive j
                const int d = c0w + ct * 16 + n;
                const int p = (jb_ & 32) + (((jb_ >> 2) & 3) * 8) + (((jb_ >> 4) & 1) * 4);
                *(uint2*)&base[d * 64 + (((p >> 3) ^ (d & 7)) * 8) + (p & 7)] =
                    make_uint2(f2bf2(acc[rt][ct][0], acc[rt][ct][1]),
                               f2bf2(acc[rt][ct][2], acc[rt][ct][3]));
            }
    }
}

// ===========================================================================
// MFMA flash attention, S^T form, exp2 softmax, register-resident P^T.
// Round-6: NO LDS, NO BARRIERS. K/V per g = 512 KB (L2-resident); each
// 16 KB tile is read by all 4 waves -> L1-serviceable. Fragments load
// directly global->VGPR at the same pre-swizzled addresses the LDS copy
// held (LDS was a verbatim tile copy). Waves free-run with phase skew:
// one wave's exp2 overlaps another's MFMA; V-load latency hides under
// mask/exp2/pack. Grid 1024 (q-split, balanced: 32+2sp tiles/block).
// ===========================================================================
__global__ __launch_bounds__(256, 4) void attn_mfma(
    const unsigned short* __restrict__ Qg,
    const unsigned short* __restrict__ Kg,
    const unsigned short* __restrict__ Vg,
    unsigned short* __restrict__ Oh)      // 4 planes of SEQ*NQ bf16
{
    const int bx = blockIdx.x;
    const int h  = bx & 15;
    const int p  = (bx >> 4) & 7;
    const int sp = (bx >> 7) & 1;          // which 64-row half of the q-block
    const int g  = bx >> 8;
    const int tid = threadIdx.x;
    const int w = tid >> 6, lane = tid & 63;
    const int n = lane & 15, quad = lane >> 4;
    const int m7 = n & 7;
    const int fo0 = (quad ^ m7) * 8;        // fragment sub-offsets (swizzled)
    const int fo1 = ((quad + 4) ^ m7) * 8;

    v8s ones;
#pragma unroll
    for (int i = 0; i < 8; i++) ones[i] = (short)0x3F80;  // bf16 1.0
    const v4f z = (v4f){0.f,0.f,0.f,0.f};

    unsigned short* Ohp = Oh + (size_t)g * ((size_t)SEQ * NQ);
    const unsigned short* Kg0 = Kg + (size_t)(g * 32) * 4096;
    const unsigned short* Vg0 = Vg + (size_t)(g * 32) * 4096;

    for (int half = 0; half < 2; half++) {
        const int qi2 = half ? (15 - p) : p;
        const int ext = 2 * qi2 + sp + 1;           // causal tile extent (>=1)
        const int rowbase = qi2 * 128 + sp * 64 + w * 16;  // wave's 16 rows

        // Q fragments: rows rowbase..rowbase+15, head h, tile 2*qi2+sp
        v8s qf0, qf1;
        {
            const unsigned short* rp =
                Qg + ((size_t)((2 * qi2 + sp) * 16 + h)) * 4096 + (w * 16 + n) * 64;
            qf0 = *(const v8s*)(rp + fo0);
            qf1 = *(const v8s*)(rp + fo1);
        }

        v4f Lacc = (v4f){0.f,0.f,0.f,0.f};
        v4f Oacc[4];
#pragma unroll
        for (int dt = 0; dt < 4; dt++) Oacc[dt] = (v4f){0.f,0.f,0.f,0.f};

        for (int t = 0; t < ext; t++) {
            const unsigned short* Kt = Kg0 + (size_t)t * 4096;
            const unsigned short* Vt = Vg0 + (size_t)t * 4096;

            // --- K fragments: 8 global loads issued up front (L1/L2 hits) ---
            v8s kf00 = *(const v8s*)&Kt[( 0 + n) * 64 + fo0];
            v8s kf01 = *(const v8s*)&Kt[( 0 + n) * 64 + fo1];
            v8s kf10 = *(const v8s*)&Kt[(16 + n) * 64 + fo0];
            v8s kf11 = *(const v8s*)&Kt[(16 + n) * 64 + fo1];
            v8s kf20 = *(const v8s*)&Kt[(32 + n) * 64 + fo0];
            v8s kf21 = *(const v8s*)&Kt[(32 + n) * 64 + fo1];
            v8s kf30 = *(const v8s*)&Kt[(48 + n) * 64 + fo0];
            v8s kf31 = *(const v8s*)&Kt[(48 + n) * 64 + fo1];

            // --- QK(t): S^T = K·Q^T (lane holds q=n, j = jt*16+quad*4+reg) ---
            v4f sc0, sc1, sc2, sc3;
            __builtin_amdgcn_s_setprio(1);
            {
                v4f tq = __builtin_amdgcn_mfma_f32_16x16x32_bf16(kf00, qf0, z, 0, 0, 0);
                sc0 = __builtin_amdgcn_mfma_f32_16x16x32_bf16(kf01, qf1, tq, 0, 0, 0);
            }
            {
                v4f tq = __builtin_amdgcn_mfma_f32_16x16x32_bf16(kf10, qf0, z, 0, 0, 0);
                sc1 = __builtin_amdgcn_mfma_f32_16x16x32_bf16(kf11, qf1, tq, 0, 0, 0);
            }
            {
                v4f tq = __builtin_amdgcn_mfma_f32_16x16x32_bf16(kf20, qf0, z, 0, 0, 0);
                sc2 = __builtin_amdgcn_mfma_f32_16x16x32_bf16(kf21, qf1, tq, 0, 0, 0);
            }
            {
                v4f tq = __builtin_amdgcn_mfma_f32_16x16x32_bf16(kf30, qf0, z, 0, 0, 0);
                sc3 = __builtin_amdgcn_mfma_f32_16x16x32_bf16(kf31, qf1, tq, 0, 0, 0);
            }
            __builtin_amdgcn_s_setprio(0);

            // --- V fragments: issue now; latency hides under mask/exp2/pack ---
            v8s vf00 = *(const v8s*)&Vt[( 0 + n) * 64 + fo0];
            v8s vf01 = *(const v8s*)&Vt[( 0 + n) * 64 + fo1];
            v8s vf10 = *(const v8s*)&Vt[(16 + n) * 64 + fo0];
            v8s vf11 = *(const v8s*)&Vt[(16 + n) * 64 + fo1];
            v8s vf20 = *(const v8s*)&Vt[(32 + n) * 64 + fo0];
            v8s vf21 = *(const v8s*)&Vt[(32 + n) * 64 + fo1];
            v8s vf30 = *(const v8s*)&Vt[(48 + n) * 64 + fo0];
            v8s vf31 = *(const v8s*)&Vt[(48 + n) * 64 + fo1];

            // --- mask (diagonal tile only; wave-uniform branch) + exp2 ---
            const int t0 = t * 64;
            if (t0 + 63 > rowbase) {
                const int qg = rowbase + n;
#pragma unroll
                for (int reg = 0; reg < 4; reg++) {
                    sc0[reg] = (t0 +  0 + quad * 4 + reg <= qg) ? sc0[reg] : -INFINITY;
                    sc1[reg] = (t0 + 16 + quad * 4 + reg <= qg) ? sc1[reg] : -INFINITY;
                    sc2[reg] = (t0 + 32 + quad * 4 + reg <= qg) ? sc2[reg] : -INFINITY;
                    sc3[reg] = (t0 + 48 + quad * 4 + reg <= qg) ? sc3[reg] : -INFINITY;
                }
            }
#pragma unroll
            for (int reg = 0; reg < 4; reg++) {
                sc0[reg] = __builtin_amdgcn_exp2f(sc0[reg]);
                sc1[reg] = __builtin_amdgcn_exp2f(sc1[reg]);
                sc2[reg] = __builtin_amdgcn_exp2f(sc2[reg]);
                sc3[reg] = __builtin_amdgcn_exp2f(sc3[reg]);
            }

            // --- P^T B-frags = C-layout registers (j-permuted PV) ---
            v8s pf0 = pack8(sc0, sc1);
            v8s pf1 = pack8(sc2, sc3);

            __builtin_amdgcn_s_setprio(1);
            // l-accumulation via MFMA: Lacc = 1^T · P^T (every reg holds l_q)
            Lacc = __builtin_amdgcn_mfma_f32_16x16x32_bf16(ones, pf0, Lacc, 0, 0, 0);
            Lacc = __builtin_amdgcn_mfma_f32_16x16x32_bf16(ones, pf1, Lacc, 0, 0, 0);

            // PV: O^T += V^T(permuted) · P^T
            Oacc[0] = __builtin_amdgcn_mfma_f32_16x16x32_bf16(vf00, pf0, Oacc[0], 0, 0, 0);
            Oacc[0] = __builtin_amdgcn_mfma_f32_16x16x32_bf16(vf01, pf1, Oacc[0], 0, 0, 0);
            Oacc[1] = __builtin_amdgcn_mfma_f32_16x16x32_bf16(vf10, pf0, Oacc[1], 0, 0, 0);
            Oacc[1] = __builtin_amdgcn_mfma_f32_16x16x32_bf16(vf11, pf1, Oacc[1], 0, 0, 0);
            Oacc[2] = __builtin_amdgcn_mfma_f32_16x16x32_bf16(vf20, pf0, Oacc[2], 0, 0, 0);
            Oacc[2] = __builtin_amdgcn_mfma_f32_16x16x32_bf16(vf21, pf1, Oacc[2], 0, 0, 0);
            Oacc[3] = __builtin_amdgcn_mfma_f32_16x16x32_bf16(vf30, pf0, Oacc[3], 0, 0, 0);
            Oacc[3] = __builtin_amdgcn_mfma_f32_16x16x32_bf16(vf31, pf1, Oacc[3], 0, 0, 0);
            __builtin_amdgcn_s_setprio(0);
        }

        // normalize (l complete per lane in Lacc[0]) & store bf16
        {
            const float inv = 0.25f / Lacc[0];   // j=0 always unmasked -> L>0
            const int row = rowbase + n;
            unsigned short* dst = Ohp + (size_t)row * NQ + h * DH + quad * 4;
#pragma unroll
            for (int dt = 0; dt < 4; dt++) {
                uint2 pk = make_uint2(f2bf2(Oacc[dt][0] * inv, Oacc[dt][1] * inv),
                                      f2bf2(Oacc[dt][2] * inv, Oacc[dt][3] * inv));
                *(uint2*)(dst + dt * 16) = pk;
            }
        }
    }
}

// ===========================================================================
// Plane reduction: Os[s][j] = bf16( sum_g Oh[g][s][j] ), fp32 accumulate.
// Pure memory op: 16 MB read + 4 MB write. 1024 blocks.
// ===========================================================================
__global__ __launch_bounds__(256) void sum4(
    const unsigned short* __restrict__ Oh,
    unsigned short* __restrict__ Os)
{
    const size_t i = ((size_t)blockIdx.x * 256 + threadIdx.x) * 8;
    const size_t plane = (size_t)SEQ * NQ;
    uint4 u0 = *(const uint4*)(Oh + i);
    uint4 u1 = *(const uint4*)(Oh + plane + i);
    uint4 u2 = *(const uint4*)(Oh + 2 * plane + i);
    uint4 u3 = *(const uint4*)(Oh + 3 * plane + i);
    unsigned int ow[4];
#pragma unroll
    for (int q = 0; q < 4; q++) {
        const unsigned int a = ((const unsigned int*)&u0)[q];
        const unsigned int b = ((const unsigned int*)&u1)[q];
        const unsigned int c = ((const unsigned int*)&u2)[q];
        const unsigned int d = ((const unsigned int*)&u3)[q];
        float lo = bf2f((unsigned short)(a & 0xffffu)) + bf2f((unsigned short)(b & 0xffffu))
                 + bf2f((unsigned short)(c & 0xffffu)) + bf2f((unsigned short)(d & 0xffffu));
        float hi = bf2f((unsigned short)(a >> 16)) + bf2f((unsigned short)(b >> 16))
                 + bf2f((unsigned short)(c >> 16)) + bf2f((unsigned short)(d >> 16));
        ow[q] = f2bf2(lo, hi);
    }
    *(uint4*)(Os + i) = make_uint4(ow[0], ow[1], ow[2], ow[3]);
}

// ===========================================================================
// GEMM 2 (MFMA): out[s][o] = sum_j Os[s][j] * Wo[o][j]. fp32 out.
// 32x64 tile, BK=64, gll16 DMA double-buffered staging (XOR swizzle, zero
// staging VALU), single barrier/iter. Grid 64x8 = 512 blocks (2/CU).
// ===========================================================================
__global__ __launch_bounds__(256, 4) void gemm_out(
    const unsigned short* __restrict__ Os,
    const unsigned short* __restrict__ Wob,
    float* __restrict__ C)
{
    __shared__ unsigned short Asb[2][2048];   // 32x64
    __shared__ unsigned short Bsb[2][4096];   // 64x64

    const int m0 = blockIdx.x * 32;
    const int n0 = blockIdx.y * 64;
    const int tid = threadIdx.x;
    const int w = tid >> 6, lane = tid & 63;
    const int n = lane & 15, quad = lane >> 4;
    const int m7 = n & 7;
    const int rw = (w & 1) * 16, cw = (w >> 1) * 32;

    const unsigned short* Ap = Os + (size_t)m0 * NQ;
    const unsigned short* Bp = Wob + (size_t)n0 * NQ;

    v4f acc[2];
    acc[0] = (v4f){0.f,0.f,0.f,0.f};
    acc[1] = (v4f){0.f,0.f,0.f,0.f};

    stage_tile32(Ap, NQ, 0, &Asb[0][0], w, lane);
    stage_tile  (Bp, NQ, 0, &Bsb[0][0], w, lane);

    for (int kb = 0; kb < NQ; kb += 64) {
        const int buf = (kb >> 6) & 1;
        __syncthreads();   // drains DMA; guards buf^1 reuse
        if (kb + 64 < NQ) {
            stage_tile32(Ap, NQ, kb + 64, &Asb[buf ^ 1][0], w, lane);
            stage_tile  (Bp, NQ, kb + 64, &Bsb[buf ^ 1][0], w, lane);
        }
#pragma unroll
        for (int kk = 0; kk < 2; kk++) {
            const int gs = ((kk * 4 + quad) ^ m7) * 8;
            v8s a  = *(const v8s*)&Asb[buf][(rw + n) * 64 + gs];
            v8s b0 = *(const v8s*)&Bsb[buf][(cw + n) * 64 + gs];
            v8s b1 = *(const v8s*)&Bsb[buf][(cw + 16 + n) * 64 + gs];
            acc[0] = __builtin_amdgcn_mfma_f32_16x16x32_bf16(a, b0, acc[0], 0, 0, 0);
            acc[1] = __builtin_amdgcn_mfma_f32_16x16x32_bf16(a, b1, acc[1], 0, 0, 0);
        }
    }

#pragma unroll
    for (int ct = 0; ct < 2; ct++)
#pragma unroll
        for (int reg = 0; reg < 4; reg++) {
            const int row = m0 + rw + quad * 4 + reg;
            const int col = n0 + cw + ct * 16 + n;
            C[(size_t)row * OUTD + col] = acc[ct][reg];
        }
}

// ===========================================================================
extern "C" void kernel_launch(void* const* d_in, const int* in_sizes, int n_in,
                              void* d_out, int out_size, void* d_ws, size_t ws_size,
                              hipStream_t stream) {
    const float* x  = (const float*)d_in[0];
    const float* Wq = (const float*)d_in[1];
    const float* Wk = (const float*)d_in[2];
    const float* Wv = (const float*)d_in[3];
    const float* Wo = (const float*)d_in[4];
    float* out = (float*)d_out;

    char* base = (char*)d_ws;
    unsigned short* Oh  = (unsigned short*)(base);
    unsigned short* xb  = (unsigned short*)(base);             // dead before attn
    unsigned short* Wqb = (unsigned short*)(base + 2097152);
    unsigned short* Wkb = (unsigned short*)(base + 3145728);
    unsigned short* Wvb = (unsigned short*)(base + 3407872);
    unsigned short* Qg  = (unsigned short*)(base + 16777216);
    unsigned short* Kg  = (unsigned short*)(base + 20971520);
    unsigned short* Vg  = (unsigned short*)(base + 22020096);
    unsigned short* Wob = (unsigned short*)(base + 23068672);
    unsigned short* Os  = Qg;   // Qg region is dead after attn_mfma

    dim3 blk(256);
    cast_all<<<dim3(1152), blk, 0, stream>>>(x, Wq, Wk, Wv, Wo,
                                             xb, Wqb, Wkb, Wvb, Wob);
    gemm_qkv<<<dim3(SEQ / 64, (NQ + 2 * NKV) / 64), blk, 0, stream>>>(
        xb, Wqb, Wkb, Wvb, Qg, Kg, Vg);
    attn_mfma<<<dim3(1024), blk, 0, stream>>>(Qg, Kg, Vg, Oh);
    sum4<<<dim3(1024), blk, 0, stream>>>(Oh, Os);
    gemm_out<<<dim3(SEQ / 32, OUTD / 64), blk, 0, stream>>>(Os, Wob, out);
}

// Round 9
// 139.292 us; speedup vs baseline: 1.3981x; 1.3981x over previous
//
#include <hip/hip_runtime.h>
#include <hip/hip_bf16.h>

// Problem constants
#define SEQ   2048
#define INF_  512          // IN dim
#define HQ    16           // query heads
#define KVH   4            // kv heads
#define DH    64           // head dim
#define NQ    (HQ*DH)      // 1024
#define NKV   (KVH*DH)     // 256
#define OUTD  512

typedef short v8s __attribute__((ext_vector_type(8)));   // 8 bf16 (4 VGPRs)
typedef float v4f __attribute__((ext_vector_type(4)));   // 4 fp32 acc

static __device__ __forceinline__ float bf2f(unsigned short u) {
    union { unsigned int i; float f; } c;
    c.i = ((unsigned int)u) << 16;
    return c.f;
}
static __device__ __forceinline__ unsigned short f2bf(float f) {  // RNE
    union { float f; unsigned int i; } c; c.f = f;
    unsigned int lsb = (c.i >> 16) & 1u;
    c.i += 0x7fffu + lsb;
    return (unsigned short)(c.i >> 16);
}
static __device__ __forceinline__ unsigned int f2bf2(float lo, float hi) { // packed cvt
    union { __hip_bfloat162 h; unsigned int u; } c;
    c.h = __float22bfloat162_rn(make_float2(lo, hi));
    return c.u;
}
// pack two v4f (8 fp32) into one bf16x8 fragment
static __device__ __forceinline__ v8s pack8(v4f a, v4f b) {
    union { v8s s; uint4 u; } c;
    c.u = make_uint4(f2bf2(a[0], a[1]), f2bf2(a[2], a[3]),
                     f2bf2(b[0], b[1]), f2bf2(b[2], b[3]));
    return c.s;
}

// async global->LDS DMA, 16B per lane; lds base must be lane-invariant
static __device__ __forceinline__ void gll16(const void* g, void* l) {
    __builtin_amdgcn_global_load_lds(
        (const __attribute__((address_space(1))) void*)g,
        (__attribute__((address_space(3))) void*)l, 16, 0, 0);
}

// Stage one 64x64 bf16 tile (row-major src, given row stride) into LDS with
// XOR group swizzle applied via SOURCE addresses: LDS slot s of row r holds
// k-group s^(r&7). Wave w stages rows w*16..w*16+15 (2 DMA instrs).
static __device__ __forceinline__ void stage_tile(
    const unsigned short* __restrict__ src, int stride, int kb,
    unsigned short* ldsbase, int w, int lane)
{
#pragma unroll
    for (int i = 0; i < 2; i++) {
        const int rl = w * 16 + i * 8 + (lane >> 3);
        const int kc = ((lane & 7) ^ (rl & 7)) * 8;
        gll16(src + (size_t)rl * stride + kb + kc,
              ldsbase + (w * 16 + i * 8) * 64);
    }
}

// Same, for a 32x64 tile (wave w stages rows w*8..w*8+7, 1 DMA instr).
static __device__ __forceinline__ void stage_tile32(
    const unsigned short* __restrict__ src, int stride, int kb,
    unsigned short* ldsbase, int w, int lane)
{
    const int rl = w * 8 + (lane >> 3);
    const int kc = ((lane & 7) ^ (rl & 7)) * 8;
    gll16(src + (size_t)rl * stride + kb + kc,
          ldsbase + (w * 8) * 64);
}

#define QSCALE 0.180336880f   // 0.125 * log2(e): scores in log2 domain -> exp2

// ===========================================================================
// Cast kernel: x/Wq/Wk/Wv/Wo fp32 -> bf16 flat copies.
// ===========================================================================
__global__ __launch_bounds__(256) void cast_all(
    const float* __restrict__ x,  const float* __restrict__ Wq,
    const float* __restrict__ Wk, const float* __restrict__ Wv,
    const float* __restrict__ Wo,
    unsigned short* __restrict__ xb,  unsigned short* __restrict__ Wqb,
    unsigned short* __restrict__ Wkb, unsigned short* __restrict__ Wvb,
    unsigned short* __restrict__ Wob)
{
    size_t i = ((size_t)blockIdx.x * 256 + threadIdx.x) * 8;
    const float* s; unsigned short* d; size_t off;
    if (i < 1048576)      { s = x;  d = xb;  off = i; }
    else if (i < 1572864) { s = Wq; d = Wqb; off = i - 1048576; }
    else if (i < 1703936) { s = Wk; d = Wkb; off = i - 1572864; }
    else if (i < 1835008) { s = Wv; d = Wvb; off = i - 1703936; }
    else                  { s = Wo; d = Wob; off = i - 1835008; }
    float4 a = *(const float4*)(s + off);
    float4 b = *(const float4*)(s + off + 4);
    *(uint4*)(d + off) = make_uint4(f2bf2(a.x, a.y), f2bf2(a.z, a.w),
                                    f2bf2(b.x, b.y), f2bf2(b.z, b.w));
}

// ===========================================================================
// GEMM 1 (MFMA): QKV projection, bf16 in -> bf16 swizzled tile buffers.
// 64x64 tile, BK=64, gll16 DMA double-buffered staging, single barrier/iter,
// zero staging VALU. Grid 32x24. Epilogue tile formats unchanged:
//   Qg[t][h], Kg[g][t]: r*64 + ((d>>3)^(r&7))*8 + (d&7)  (Q pre-scaled)
//   Vg[g][t]: d*64 + swizzled j-permuted position.
// ===========================================================================
__global__ __launch_bounds__(256, 4) void gemm_qkv(
    const unsigned short* __restrict__ xb,
    const unsigned short* __restrict__ Wqb,
    const unsigned short* __restrict__ Wkb,
    const unsigned short* __restrict__ Wvb,
    unsigned short* __restrict__ Qg,
    unsigned short* __restrict__ Kg,
    unsigned short* __restrict__ Vg)
{
    __shared__ unsigned short Asb[2][4096];
    __shared__ unsigned short Bsb[2][4096];

    const int m0 = blockIdx.x * 64;
    const int n0 = blockIdx.y * 64;

    const unsigned short* Bp; int role;   // 0=Q 1=K 2=V
    if (n0 < NQ)            { Bp = Wqb + (size_t)n0 * INF_;              role = 0; }
    else if (n0 < NQ + NKV) { Bp = Wkb + (size_t)(n0 - NQ) * INF_;       role = 1; }
    else                    { Bp = Wvb + (size_t)(n0 - NQ - NKV) * INF_; role = 2; }

    const int tid = threadIdx.x;
    const int w = tid >> 6, lane = tid & 63;
    const int n = lane & 15, quad = lane >> 4;
    const int m7 = n & 7;
    const int r0w = (w & 1) * 32, c0w = (w >> 1) * 32;
    const unsigned short* Ap = xb + (size_t)m0 * INF_;

    v4f acc[2][2];
#pragma unroll
    for (int rt = 0; rt < 2; rt++)
#pragma unroll
        for (int ct = 0; ct < 2; ct++) acc[rt][ct] = (v4f){0.f,0.f,0.f,0.f};

    stage_tile(Ap, INF_, 0, &Asb[0][0], w, lane);
    stage_tile(Bp, INF_, 0, &Bsb[0][0], w, lane);

    for (int kb = 0; kb < INF_; kb += 64) {
        const int buf = (kb >> 6) & 1;
        __syncthreads();   // drains DMA; guards buf^1 reuse
        if (kb + 64 < INF_) {
            stage_tile(Ap, INF_, kb + 64, &Asb[buf ^ 1][0], w, lane);
            stage_tile(Bp, INF_, kb + 64, &Bsb[buf ^ 1][0], w, lane);
        }
#pragma unroll
        for (int kk = 0; kk < 2; kk++) {
            const int gs = ((kk * 4 + quad) ^ m7) * 8;
            v8s a0 = *(const v8s*)&Asb[buf][(r0w + n) * 64 + gs];
            v8s a1 = *(const v8s*)&Asb[buf][(r0w + 16 + n) * 64 + gs];
            v8s b0 = *(const v8s*)&Bsb[buf][(c0w + n) * 64 + gs];
            v8s b1 = *(const v8s*)&Bsb[buf][(c0w + 16 + n) * 64 + gs];
            acc[0][0] = __builtin_amdgcn_mfma_f32_16x16x32_bf16(a0, b0, acc[0][0], 0, 0, 0);
            acc[0][1] = __builtin_amdgcn_mfma_f32_16x16x32_bf16(a0, b1, acc[0][1], 0, 0, 0);
            acc[1][0] = __builtin_amdgcn_mfma_f32_16x16x32_bf16(a1, b0, acc[1][0], 0, 0, 0);
            acc[1][1] = __builtin_amdgcn_mfma_f32_16x16x32_bf16(a1, b1, acc[1][1], 0, 0, 0);
        }
    }

    const int t = m0 >> 6;
    if (role == 0) {
        unsigned short* base = Qg + ((size_t)(t * 16 + (n0 >> 6))) * 4096;
#pragma unroll
        for (int rt = 0; rt < 2; rt++)
#pragma unroll
            for (int ct = 0; ct < 2; ct++)
#pragma unroll
                for (int reg = 0; reg < 4; reg++) {
                    const int r = r0w + rt * 16 + quad * 4 + reg;
                    const int d = c0w + ct * 16 + n;
                    base[r * 64 + (((d >> 3) ^ (r & 7)) * 8) + (d & 7)] =
                        f2bf(acc[rt][ct][reg] * QSCALE);
                }
    } else if (role == 1) {
        const int g = (n0 - NQ) >> 6;
        unsigned short* base = Kg + ((size_t)(g * 32 + t)) * 4096;
#pragma unroll
        for (int rt = 0; rt < 2; rt++)
#pragma unroll
            for (int ct = 0; ct < 2; ct++)
#pragma unroll
                for (int reg = 0; reg < 4; reg++) {
                    const int r = r0w + rt * 16 + quad * 4 + reg;
                    const int d = c0w + ct * 16 + n;
                    base[r * 64 + (((d >> 3) ^ (r & 7)) * 8) + (d & 7)] =
                        f2bf(acc[rt][ct][reg]);
                }
    } else {
        const int g = (n0 - NQ - NKV) >> 6;
        unsigned short* base = Vg + ((size_t)(g * 32 + t)) * 4096;
#pragma unroll
        for (int rt = 0; rt < 2; rt++)
#pragma unroll
            for (int ct = 0; ct < 2; ct++) {
                const int jb_ = r0w + rt * 16 + quad * 4;  // 4 consecutive j
                const int d = c0w + ct * 16 + n;
                const int p = (jb_ & 32) + (((jb_ >> 2) & 3) * 8) + (((jb_ >> 4) & 1) * 4);
                *(uint2*)&base[d * 64 + (((p >> 3) ^ (d & 7)) * 8) + (p & 7)] =
                    make_uint2(f2bf2(acc[rt][ct][0], acc[rt][ct][1]),
                               f2bf2(acc[rt][ct][2], acc[rt][ct][3]));
            }
    }
}

// ===========================================================================
// MFMA flash attention, S^T form, exp2 softmax, register-resident P^T.
// Round-9: 2 HEADS PER BLOCK (round-7 theory, round-4 code shape: score
// arrays with fully-unrolled constant-index loops, measured-good form).
// All heads share K_g/V_g tiles, so staging one tile serves 2 heads: per
// wave-tile 16 ds_reads feed 36 MFMAs (was 18). Grid 512 = 8 head-pairs
// x 8p x 2sp x 4g, 2 blocks/CU, LB(256,2). Balanced: 32+2sp tiles/block.
// ===========================================================================
__global__ __launch_bounds__(256, 2) void attn_mfma(
    const unsigned short* __restrict__ Qg,
    const unsigned short* __restrict__ Kg,
    const unsigned short* __restrict__ Vg,
    unsigned short* __restrict__ Oh)      // 4 planes of SEQ*NQ bf16
{
    __shared__ unsigned short Ksb[2][4096];
    __shared__ unsigned short Vsb[2][4096];

    const int bx = blockIdx.x;
    const int hg = bx & 7;                 // head pair: heads 2hg, 2hg+1
    const int p  = (bx >> 3) & 7;
    const int sp = (bx >> 6) & 1;          // which 64-row half of the q-block
    const int g  = bx >> 7;
    const int tid = threadIdx.x;
    const int w = tid >> 6, lane = tid & 63;
    const int n = lane & 15, quad = lane >> 4;
    const int m7 = n & 7;
    const int fo0 = (quad ^ m7) * 8;       // fragment sub-offsets (swizzled)
    const int fo1 = ((quad + 4) ^ m7) * 8;

    v8s ones;
#pragma unroll
    for (int i = 0; i < 8; i++) ones[i] = (short)0x3F80;  // bf16 1.0
    const v4f z = (v4f){0.f,0.f,0.f,0.f};

    unsigned short* Ohp = Oh + (size_t)g * ((size_t)SEQ * NQ);

    for (int half = 0; half < 2; half++) {
        const int qi2 = half ? (15 - p) : p;
        const int ext = 2 * qi2 + sp + 1;           // causal tile extent (>=1)
        const int rowbase = qi2 * 128 + sp * 64 + w * 16;  // wave's 16 rows

        if (half) __syncthreads();   // all waves done with half-0 buffers

        // stage tile 0 -> buf 0 (first loop barrier drains the DMA)
        {
            const size_t off = ((size_t)(g * 32)) * 4096 + w * 1024 + lane * 8;
            gll16(Kg + off,       &Ksb[0][w * 1024]);
            gll16(Kg + off + 512, &Ksb[0][w * 1024 + 512]);
            gll16(Vg + off,       &Vsb[0][w * 1024]);
            gll16(Vg + off + 512, &Vsb[0][w * 1024 + 512]);
        }

        // Q fragments for both heads (rows rowbase..rowbase+15)
        v8s qa0, qa1, qb0, qb1;
        {
            const unsigned short* rpA =
                Qg + ((size_t)((2 * qi2 + sp) * 16 + hg * 2)) * 4096 + (w * 16 + n) * 64;
            const unsigned short* rpB = rpA + 4096;
            qa0 = *(const v8s*)(rpA + fo0);
            qa1 = *(const v8s*)(rpA + fo1);
            qb0 = *(const v8s*)(rpB + fo0);
            qb1 = *(const v8s*)(rpB + fo1);
        }

        v4f LA = (v4f){0.f,0.f,0.f,0.f};
        v4f LB = (v4f){0.f,0.f,0.f,0.f};
        v4f OA[4], OB[4];
#pragma unroll
        for (int dt = 0; dt < 4; dt++) { OA[dt] = z; OB[dt] = z; }

        for (int tt = 0; tt < ext; tt++) {
            const int buf = tt & 1;
            __syncthreads();          // drains DMA; guards buf^1 reuse
            if (tt + 1 < ext) {
                const size_t off = ((size_t)(g * 32 + tt + 1)) * 4096 + w * 1024 + lane * 8;
                const int nb = buf ^ 1;
                gll16(Kg + off,       &Ksb[nb][w * 1024]);
                gll16(Kg + off + 512, &Ksb[nb][w * 1024 + 512]);
                gll16(Vg + off,       &Vsb[nb][w * 1024]);
                gll16(Vg + off + 512, &Vsb[nb][w * 1024 + 512]);
            }
            const unsigned short* Kb = Ksb[buf];
            const unsigned short* Vb = Vsb[buf];

            // S^T = K·Q^T for both heads (one kf pair feeds 4 MFMAs)
            v4f sa[4], sb[4];
            __builtin_amdgcn_s_setprio(1);
#pragma unroll
            for (int jt = 0; jt < 4; jt++) {
                const int kr = (jt * 16 + n) * 64;
                v8s k0 = *(const v8s*)&Kb[kr + fo0];
                v8s k1 = *(const v8s*)&Kb[kr + fo1];
                v4f ta = __builtin_amdgcn_mfma_f32_16x16x32_bf16(k0, qa0, z, 0, 0, 0);
                sa[jt] = __builtin_amdgcn_mfma_f32_16x16x32_bf16(k1, qa1, ta, 0, 0, 0);
                v4f tb = __builtin_amdgcn_mfma_f32_16x16x32_bf16(k0, qb0, z, 0, 0, 0);
                sb[jt] = __builtin_amdgcn_mfma_f32_16x16x32_bf16(k1, qb1, tb, 0, 0, 0);
            }
            __builtin_amdgcn_s_setprio(0);

            // mask (diagonal tile only; wave-uniform branch) + exp2, both heads
            const int t0 = tt * 64;
            if (t0 + 63 > rowbase) {
                const int qg = rowbase + n;
#pragma unroll
                for (int jt = 0; jt < 4; jt++) {
                    const int jg = t0 + jt * 16 + quad * 4;
#pragma unroll
                    for (int reg = 0; reg < 4; reg++) {
                        const bool keep = (jg + reg <= qg);
                        sa[jt][reg] = keep ? sa[jt][reg] : -INFINITY;
                        sb[jt][reg] = keep ? sb[jt][reg] : -INFINITY;
                    }
                }
            }
#pragma unroll
            for (int jt = 0; jt < 4; jt++)
#pragma unroll
                for (int reg = 0; reg < 4; reg++) {
                    sa[jt][reg] = __builtin_amdgcn_exp2f(sa[jt][reg]); // 2^-inf = 0
                    sb[jt][reg] = __builtin_amdgcn_exp2f(sb[jt][reg]);
                }

            // P^T B-frags = C-layout registers (j-permuted PV)
            v8s pA0 = pack8(sa[0], sa[1]);
            v8s pA1 = pack8(sa[2], sa[3]);
            v8s pB0 = pack8(sb[0], sb[1]);
            v8s pB1 = pack8(sb[2], sb[3]);

            __builtin_amdgcn_s_setprio(1);
            // l-accumulation via MFMA (every reg holds l_q)
            LA = __builtin_amdgcn_mfma_f32_16x16x32_bf16(ones, pA0, LA, 0, 0, 0);
            LA = __builtin_amdgcn_mfma_f32_16x16x32_bf16(ones, pA1, LA, 0, 0, 0);
            LB = __builtin_amdgcn_mfma_f32_16x16x32_bf16(ones, pB0, LB, 0, 0, 0);
            LB = __builtin_amdgcn_mfma_f32_16x16x32_bf16(ones, pB1, LB, 0, 0, 0);

            // PV: O^T += V^T(permuted) · P^T (one vf pair feeds 4 MFMAs)
#pragma unroll
            for (int dt = 0; dt < 4; dt++) {
                const int vr = (dt * 16 + n) * 64;
                v8s v0 = *(const v8s*)&Vb[vr + fo0];
                v8s v1 = *(const v8s*)&Vb[vr + fo1];
                OA[dt] = __builtin_amdgcn_mfma_f32_16x16x32_bf16(v0, pA0, OA[dt], 0, 0, 0);
                OA[dt] = __builtin_amdgcn_mfma_f32_16x16x32_bf16(v1, pA1, OA[dt], 0, 0, 0);
                OB[dt] = __builtin_amdgcn_mfma_f32_16x16x32_bf16(v0, pB0, OB[dt], 0, 0, 0);
                OB[dt] = __builtin_amdgcn_mfma_f32_16x16x32_bf16(v1, pB1, OB[dt], 0, 0, 0);
            }
            __builtin_amdgcn_s_setprio(0);
        }

        // normalize (l complete per lane) & store bf16, both heads
        {
            const float invA = 0.25f / LA[0];   // j=0 always unmasked -> L>0
            const float invB = 0.25f / LB[0];
            const int row = rowbase + n;
            unsigned short* dA = Ohp + (size_t)row * NQ + (hg * 2) * DH + quad * 4;
            unsigned short* dB = dA + DH;
#pragma unroll
            for (int dt = 0; dt < 4; dt++) {
                uint2 pkA = make_uint2(f2bf2(OA[dt][0] * invA, OA[dt][1] * invA),
                                       f2bf2(OA[dt][2] * invA, OA[dt][3] * invA));
                *(uint2*)(dA + dt * 16) = pkA;
                uint2 pkB = make_uint2(f2bf2(OB[dt][0] * invB, OB[dt][1] * invB),
                                       f2bf2(OB[dt][2] * invB, OB[dt][3] * invB));
                *(uint2*)(dB + dt * 16) = pkB;
            }
        }
    }
}

// ===========================================================================
// Plane reduction: Os[s][j] = bf16( sum_g Oh[g][s][j] ), fp32 accumulate.
// Pure memory op: 16 MB read + 4 MB write. 1024 blocks.
// ===========================================================================
__global__ __launch_bounds__(256) void sum4(
    const unsigned short* __restrict__ Oh,
    unsigned short* __restrict__ Os)
{
    const size_t i = ((size_t)blockIdx.x * 256 + threadIdx.x) * 8;
    const size_t plane = (size_t)SEQ * NQ;
    uint4 u0 = *(const uint4*)(Oh + i);
    uint4 u1 = *(const uint4*)(Oh + plane + i);
    uint4 u2 = *(const uint4*)(Oh + 2 * plane + i);
    uint4 u3 = *(const uint4*)(Oh + 3 * plane + i);
    unsigned int ow[4];
#pragma unroll
    for (int q = 0; q < 4; q++) {
        const unsigned int a = ((const unsigned int*)&u0)[q];
        const unsigned int b = ((const unsigned int*)&u1)[q];
        const unsigned int c = ((const unsigned int*)&u2)[q];
        const unsigned int d = ((const unsigned int*)&u3)[q];
        float lo = bf2f((unsigned short)(a & 0xffffu)) + bf2f((unsigned short)(b & 0xffffu))
                 + bf2f((unsigned short)(c & 0xffffu)) + bf2f((unsigned short)(d & 0xffffu));
        float hi = bf2f((unsigned short)(a >> 16)) + bf2f((unsigned short)(b >> 16))
                 + bf2f((unsigned short)(c >> 16)) + bf2f((unsigned short)(d >> 16));
        ow[q] = f2bf2(lo, hi);
    }
    *(uint4*)(Os + i) = make_uint4(ow[0], ow[1], ow[2], ow[3]);
}

// ===========================================================================
// GEMM 2 (MFMA): out[s][o] = sum_j Os[s][j] * Wo[o][j]. fp32 out.
// 32x64 tile, BK=64, gll16 DMA double-buffered staging (XOR swizzle, zero
// staging VALU), single barrier/iter. Grid 64x8 = 512 blocks (2/CU).
// ===========================================================================
__global__ __launch_bounds__(256, 4) void gemm_out(
    const unsigned short* __restrict__ Os,
    const unsigned short* __restrict__ Wob,
    float* __restrict__ C)
{
    __shared__ unsigned short Asb[2][2048];   // 32x64
    __shared__ unsigned short Bsb[2][4096];   // 64x64

    const int m0 = blockIdx.x * 32;
    const int n0 = blockIdx.y * 64;
    const int tid = threadIdx.x;
    const int w = tid >> 6, lane = tid & 63;
    const int n = lane & 15, quad = lane >> 4;
    const int m7 = n & 7;
    const int rw = (w & 1) * 16, cw = (w >> 1) * 32;

    const unsigned short* Ap = Os + (size_t)m0 * NQ;
    const unsigned short* Bp = Wob + (size_t)n0 * NQ;

    v4f acc[2];
    acc[0] = (v4f){0.f,0.f,0.f,0.f};
    acc[1] = (v4f){0.f,0.f,0.f,0.f};

    stage_tile32(Ap, NQ, 0, &Asb[0][0], w, lane);
    stage_tile  (Bp, NQ, 0, &Bsb[0][0], w, lane);

    for (int kb = 0; kb < NQ; kb += 64) {
        const int buf = (kb >> 6) & 1;
        __syncthreads();   // drains DMA; guards buf^1 reuse
        if (kb + 64 < NQ) {
            stage_tile32(Ap, NQ, kb + 64, &Asb[buf ^ 1][0], w, lane);
            stage_tile  (Bp, NQ, kb + 64, &Bsb[buf ^ 1][0], w, lane);
        }
#pragma unroll
        for (int kk = 0; kk < 2; kk++) {
            const int gs = ((kk * 4 + quad) ^ m7) * 8;
            v8s a  = *(const v8s*)&Asb[buf][(rw + n) * 64 + gs];
            v8s b0 = *(const v8s*)&Bsb[buf][(cw + n) * 64 + gs];
            v8s b1 = *(const v8s*)&Bsb[buf][(cw + 16 + n) * 64 + gs];
            acc[0] = __builtin_amdgcn_mfma_f32_16x16x32_bf16(a, b0, acc[0], 0, 0, 0);
            acc[1] = __builtin_amdgcn_mfma_f32_16x16x32_bf16(a, b1, acc[1], 0, 0, 0);
        }
    }

#pragma unroll
    for (int ct = 0; ct < 2; ct++)
#pragma unroll
        for (int reg = 0; reg < 4; reg++) {
            const int row = m0 + rw + quad * 4 + reg;
            const int col = n0 + cw + ct * 16 + n;
            C[(size_t)row * OUTD + col] = acc[ct][reg];
        }
}

// ===========================================================================
extern "C" void kernel_launch(void* const* d_in, const int* in_sizes, int n_in,
                              void* d_out, int out_size, void* d_ws, size_t ws_size,
                              hipStream_t stream) {
    const float* x  = (const float*)d_in[0];
    const float* Wq = (const float*)d_in[1];
    const float* Wk = (const float*)d_in[2];
    const float* Wv = (const float*)d_in[3];
    const float* Wo = (const float*)d_in[4];
    float* out = (float*)d_out;

    char* base = (char*)d_ws;
    unsigned short* Oh  = (unsigned short*)(base);
    unsigned short* xb  = (unsigned short*)(base);             // dead before attn
    unsigned short* Wqb = (unsigned short*)(base + 2097152);
    unsigned short* Wkb = (unsigned short*)(base + 3145728);
    unsigned short* Wvb = (unsigned short*)(base + 3407872);
    unsigned short* Qg  = (unsigned short*)(base + 16777216);
    unsigned short* Kg  = (unsigned short*)(base + 20971520);
    unsigned short* Vg  = (unsigned short*)(base + 22020096);
    unsigned short* Wob = (unsigned short*)(base + 23068672);
    unsigned short* Os  = Qg;   // Qg region is dead after attn_mfma

    dim3 blk(256);
    cast_all<<<dim3(1152), blk, 0, stream>>>(x, Wq, Wk, Wv, Wo,
                                             xb, Wqb, Wkb, Wvb, Wob);
    gemm_qkv<<<dim3(SEQ / 64, (NQ + 2 * NKV) / 64), blk, 0, stream>>>(
        xb, Wqb, Wkb, Wvb, Qg, Kg, Vg);
    attn_mfma<<<dim3(512), blk, 0, stream>>>(Qg, Kg, Vg, Oh);
    sum4<<<dim3(1024), blk, 0, stream>>>(Oh, Os);
    gemm_out<<<dim3(SEQ / 32, OUTD / 64), blk, 0, stream>>>(Os, Wob, out);
}